// Round 3
// baseline (52188.788 us; speedup 1.0000x reference)
//
#include <hip/hip_runtime.h>
#include <cstdint>
#include <cstddef>

// FC_LSTM on MI355X — Round 3: INPUTS ARE FLOAT32 (bf16-quantized values),
// output float32. R1/R2 NaN forensics: reading f32 inputs as bf16 pairs made
// odd u16s (mantissa bits) decode to huge exponents -> f16 pack -> Inf ->
// fdot2(Inf, 0) = NaN at t=0, independent of output dtype. Fix: float reads.
// Phase 0: repack weights f32 -> f16 pairs, k-major (transposed) for L2 streaming.
// Phase 1: xw = x@Wx.T + (bx+bh) via bf16 MFMA (f32->bf16 exact), f16 out in ws.
// Phase 2: 32 WGs (one per batch row), 1024 thr; v_dot2_f32_f16 matvecs,
//          fp32 state in LDS, f32 output stores.

typedef unsigned short u16;
typedef unsigned int   u32;
typedef float  v4f __attribute__((ext_vector_type(4)));
typedef short  v8s __attribute__((ext_vector_type(8)));
typedef _Float16 h2 __attribute__((ext_vector_type(2)));

#define SEQ 2048
#define NB  32
#define HID 256
#define G4  1024
#define FIN 128
#define COFF (2049*NB*HID)   // element offset of memorys half of d_out

__device__ __forceinline__ u16 f2bf(float f) {
  u32 u = __builtin_bit_cast(u32, f);
  u32 r = (u + 0x7fffu + ((u >> 16) & 1u)) >> 16;
  return (u16)r;
}
__device__ __forceinline__ u16 f2h_bits(float f) {
  _Float16 h = (_Float16)f;
  return __builtin_bit_cast(u16, h);
}
__device__ __forceinline__ u32 pack2f(float a, float b) {
  u32 lo = f2h_bits(a);
  u32 hi = f2h_bits(b);
  return lo | (hi << 16);
}
__device__ __forceinline__ float fd(u32 w, u32 u, float acc) {
  h2 hw = __builtin_bit_cast(h2, w);
  h2 hu = __builtin_bit_cast(h2, u);
  return __builtin_amdgcn_fdot2(hw, hu, acc, false);
}
__device__ __forceinline__ float sigm(float v) { return 1.f / (1.f + __expf(-v)); }

// ---------------- Phase 0: weight repack (f32 -> f16 pairs, k-major) --------
// ws uint layout:
//   [0      .. 131072) WhT2 : pair j (k=2j,2j+1), col n of 1024   -> Wh[n][k]
//   [131072 .. 196608) WpT2 : 512 cols = [Wci cols | Wcf cols]
//   [196608 .. 229376) WcoT2: 256 cols
//   [229376 .. 294912) WxT2 : j<64, 1024 cols (fallback path)
__global__ __launch_bounds__(256) void prep_weights(
    const float* __restrict__ Wh, const float* __restrict__ Wci,
    const float* __restrict__ Wcf, const float* __restrict__ Wco,
    const float* __restrict__ Wx, u32* __restrict__ wsu)
{
  int i = blockIdx.x * 256 + threadIdx.x;
  if (i < 131072) {
    int j = i >> 10, n = i & 1023;
    wsu[i] = pack2f(Wh[n*256 + 2*j], Wh[n*256 + 2*j + 1]);
  } else if (i < 196608) {
    int l = i - 131072; int j = l >> 9, n = l & 511;
    const float* src = (n < 256) ? (Wci + n*256) : (Wcf + (n-256)*256);
    wsu[i] = pack2f(src[2*j], src[2*j + 1]);
  } else if (i < 229376) {
    int l = i - 196608; int j = l >> 8, n = l & 255;
    wsu[i] = pack2f(Wco[n*256 + 2*j], Wco[n*256 + 2*j + 1]);
  } else if (i < 294912) {
    int l = i - 229376; int j = l >> 10, n = l & 1023;
    wsu[i] = pack2f(Wx[n*128 + 2*j], Wx[n*128 + 2*j + 1]);
  }
}

// ---------------- Phase 1: xw GEMM (bf16 MFMA, f32 inputs) ------------------
// M = 65536 rows (r = b*2048 + t), N = 1024, K = 128. Verified fragment maps:
// A/B: row = lane&15, k = (lane>>4)*8 + j ; D: col = lane&15, row = quad*4+reg.
__global__ __launch_bounds__(256) void xw_gemm(
    const float* __restrict__ x, const float* __restrict__ Wx,
    const float* __restrict__ bx, const float* __restrict__ bh,
    u16* __restrict__ xw)
{
  int wave = threadIdx.x >> 6, lane = threadIdx.x & 63;
  int s = lane & 15, q = lane >> 4;
  int mtile = blockIdx.x;              // 0..4095
  int ntile = blockIdx.y * 4 + wave;   // 0..63
  const float* xa = x  + (size_t)(mtile*16 + s) * 128 + q*8;
  const float* wb = Wx + (size_t)(ntile*16 + s) * 128 + q*8;
  v4f acc = {0.f, 0.f, 0.f, 0.f};
#pragma unroll
  for (int ko = 0; ko < 4; ++ko) {
    float4 a0 = *reinterpret_cast<const float4*>(xa + ko*32);
    float4 a1 = *reinterpret_cast<const float4*>(xa + ko*32 + 4);
    float4 b0 = *reinterpret_cast<const float4*>(wb + ko*32);
    float4 b1 = *reinterpret_cast<const float4*>(wb + ko*32 + 4);
    v8s a, b;
    a[0]=(short)f2bf(a0.x); a[1]=(short)f2bf(a0.y); a[2]=(short)f2bf(a0.z); a[3]=(short)f2bf(a0.w);
    a[4]=(short)f2bf(a1.x); a[5]=(short)f2bf(a1.y); a[6]=(short)f2bf(a1.z); a[7]=(short)f2bf(a1.w);
    b[0]=(short)f2bf(b0.x); b[1]=(short)f2bf(b0.y); b[2]=(short)f2bf(b0.z); b[3]=(short)f2bf(b0.w);
    b[4]=(short)f2bf(b1.x); b[5]=(short)f2bf(b1.y); b[6]=(short)f2bf(b1.z); b[7]=(short)f2bf(b1.w);
    acc = __builtin_amdgcn_mfma_f32_16x16x32_bf16(a, b, acc, 0, 0, 0);
  }
  int n = ntile*16 + s;
  float bias = bx[n] + bh[n];
#pragma unroll
  for (int p = 0; p < 4; ++p) {
    int m = mtile*16 + q*4 + p;
    int bb = m >> 11, t = m & 2047;   // r = b*2048 + t
    xw[(size_t)(t*NB + bb) * G4 + n] = f2h_bits(acc[p] + bias);
  }
}

// ---------------- Phase 2: recurrent scan -----------------------------------
template<bool PRE>
__global__ __launch_bounds__(1024) void lstm_scan(
    const u32* __restrict__ wsu, const void* __restrict__ xsrc_v,
    const float* __restrict__ bx, const float* __restrict__ bh,
    const float* __restrict__ bci, const float* __restrict__ bcf,
    const float* __restrict__ bco, float* __restrict__ out)
{
  const int b = blockIdx.x, tid = threadIdx.x;
  const u32* WhT2  = wsu;
  const u32* WpT2  = wsu + 131072;
  const u32* WcoT2 = wsu + 196608;
  const u32* WxT2  = wsu + 229376;

  __shared__ __align__(16) float s_i[256], s_f[256], s_g[256], s_op[256];
  __shared__ __align__(16) float s_c[256], s_cn[256], s_z[4][256];
  __shared__ __align__(16) u16 s_u[512];    // f16 bits: h [0:256), c [256:512)
  __shared__ __align__(16) u16 s_cnh[256];  // f16 bits of c_new
  __shared__ __align__(16) u16 s_x[128];    // f16 bits of x row (fallback only)
  __shared__ float s_bci[256], s_bcf[256], s_bco[256];
  __shared__ float s_bias[1024];

  if (tid < 256) {
    s_c[tid] = 0.f; s_u[tid] = 0; s_u[256 + tid] = 0;
    s_bci[tid] = bci[tid];
    s_bcf[tid] = bcf[tid];
    s_bco[tid] = bco[tid];
    out[b*HID + tid] = 0.f;          // h0 = 0
    out[COFF + b*HID + tid] = 0.f;   // c0 = 0
  }
  if (!PRE) s_bias[tid] = bx[tid] + bh[tid];
  __syncthreads();

  for (int t = 0; t < SEQ; ++t) {
    u16 xw_raw = 0;
    if (PRE) {
      // prefetch early; consumed after the dot loops (latency hidden)
      const u16* xw = (const u16*)xsrc_v;
      xw_raw = xw[(size_t)(t*NB + b) * G4 + tid];
    } else {
      if (tid < 128) {
        const float* xr = (const float*)xsrc_v + (size_t)(b*SEQ + t) * FIN;
        s_x[tid] = f2h_bits(xr[tid]);
      }
      __syncthreads();
    }

    // y[tid] = h . Wh[tid,:]  (+ c . Wp[tid,:] for i,f cols)
    float acc0 = 0.f, acc1 = 0.f;
#pragma unroll 4
    for (int j0 = 0; j0 < 128; j0 += 8) {
      uint4 lo = *reinterpret_cast<const uint4*>(&s_u[2*j0]);
      uint4 hi = *reinterpret_cast<const uint4*>(&s_u[2*j0 + 8]);
      const u32* w = WhT2 + j0*1024 + tid;
      acc0 = fd(w[0],    lo.x, acc0); acc1 = fd(w[1024], lo.y, acc1);
      acc0 = fd(w[2048], lo.z, acc0); acc1 = fd(w[3072], lo.w, acc1);
      acc0 = fd(w[4096], hi.x, acc0); acc1 = fd(w[5120], hi.y, acc1);
      acc0 = fd(w[6144], hi.z, acc0); acc1 = fd(w[7168], hi.w, acc1);
    }
    if (!PRE) {
#pragma unroll 2
      for (int j0 = 0; j0 < 64; j0 += 8) {
        uint4 lo = *reinterpret_cast<const uint4*>(&s_x[2*j0]);
        uint4 hi = *reinterpret_cast<const uint4*>(&s_x[2*j0 + 8]);
        const u32* w = WxT2 + j0*1024 + tid;
        acc0 = fd(w[0],    lo.x, acc0); acc1 = fd(w[1024], lo.y, acc1);
        acc0 = fd(w[2048], lo.z, acc0); acc1 = fd(w[3072], lo.w, acc1);
        acc0 = fd(w[4096], hi.x, acc0); acc1 = fd(w[5120], hi.y, acc1);
        acc0 = fd(w[6144], hi.z, acc0); acc1 = fd(w[7168], hi.w, acc1);
      }
    }
    if (tid < 512) {  // peephole for i,f over old c (waves 0..7, uniform)
#pragma unroll 4
      for (int j0 = 0; j0 < 128; j0 += 8) {
        uint4 lo = *reinterpret_cast<const uint4*>(&s_u[256 + 2*j0]);
        uint4 hi = *reinterpret_cast<const uint4*>(&s_u[256 + 2*j0 + 8]);
        const u32* w = WpT2 + j0*512 + tid;
        acc0 = fd(w[0],    lo.x, acc0); acc1 = fd(w[512],  lo.y, acc1);
        acc0 = fd(w[1024], lo.z, acc0); acc1 = fd(w[1536], lo.w, acc1);
        acc0 = fd(w[2048], hi.x, acc0); acc1 = fd(w[2560], hi.y, acc1);
        acc0 = fd(w[3072], hi.z, acc0); acc1 = fd(w[3584], hi.w, acc1);
      }
    }
    float acc = acc0 + acc1;
    if (PRE) {
      _Float16 hv = __builtin_bit_cast(_Float16, xw_raw);
      acc += (float)hv;
    } else {
      acc += s_bias[tid];
    }

    int gate = tid >> 8, n = tid & 255;
    if (gate == 0)      s_i[n]  = sigm(acc + s_bci[n]);
    else if (gate == 1) s_f[n]  = sigm(acc + s_bcf[n]);
    else if (gate == 2) s_op[n] = acc;                 // bco + peephole later
    else                s_g[n]  = tanhf(acc);
    __syncthreads();

    if (tid < 256) {
      float cn = s_f[tid]*s_c[tid] + s_i[tid]*s_g[tid];
      s_cn[tid] = cn; s_c[tid] = cn;
      s_cnh[tid] = f2h_bits(cn);
      out[COFF + (size_t)(t+1)*(NB*HID) + b*HID + tid] = cn;
    }
    __syncthreads();

    {   // o-peephole: z = Wco . c_new, K split 4 ways across the 1024 threads
      int nn = tid & 255, part = tid >> 8;
      float z0 = 0.f, z1 = 0.f;
#pragma unroll
      for (int j0 = part*32; j0 < part*32 + 32; j0 += 8) {
        uint4 lo = *reinterpret_cast<const uint4*>(&s_cnh[2*j0]);
        uint4 hi = *reinterpret_cast<const uint4*>(&s_cnh[2*j0 + 8]);
        const u32* w = WcoT2 + j0*256 + nn;
        z0 = fd(w[0],    lo.x, z0); z1 = fd(w[256],  lo.y, z1);
        z0 = fd(w[512],  lo.z, z0); z1 = fd(w[768],  lo.w, z1);
        z0 = fd(w[1024], hi.x, z0); z1 = fd(w[1280], hi.y, z1);
        z0 = fd(w[1536], hi.z, z0); z1 = fd(w[1792], hi.w, z1);
      }
      s_z[part][nn] = z0 + z1;
    }
    __syncthreads();

    if (tid < 256) {
      float z = s_z[0][tid] + s_z[1][tid] + s_z[2][tid] + s_z[3][tid]
              + s_op[tid] + s_bco[tid];
      float o  = sigm(z);
      float hn = o * tanhf(s_cn[tid]);
      out[(size_t)(t+1)*(NB*HID) + b*HID + tid] = hn;
      s_u[tid] = f2h_bits(hn);        // h for next step
      s_u[256 + tid] = s_cnh[tid];    // c for next step
    }
    __syncthreads();
  }
}

// ---------------- launch ----------------------------------------------------
extern "C" void kernel_launch(void* const* d_in, const int* in_sizes, int n_in,
                              void* d_out, int out_size, void* d_ws, size_t ws_size,
                              hipStream_t stream)
{
  const float* x   = (const float*)d_in[0];
  const float* Wx  = (const float*)d_in[1];
  const float* bx  = (const float*)d_in[2];
  const float* Wh  = (const float*)d_in[3];
  const float* bh  = (const float*)d_in[4];
  const float* Wci = (const float*)d_in[5];
  const float* bci = (const float*)d_in[6];
  const float* Wcf = (const float*)d_in[7];
  const float* bcf = (const float*)d_in[8];
  const float* Wco = (const float*)d_in[9];
  const float* bco = (const float*)d_in[10];
  float* out = (float*)d_out;
  u32* wsu = (u32*)d_ws;
  u16* xw  = (u16*)((char*)d_ws + 294912ull*4);

  const size_t NEED = 294912ull*4 + (size_t)SEQ*NB*G4*2;  // ~129 MB
  const bool pre = (ws_size >= NEED);   // constant across calls -> capture-safe

  hipLaunchKernelGGL(prep_weights, dim3(1152), dim3(256), 0, stream,
                     Wh, Wci, Wcf, Wco, Wx, wsu);
  if (pre) {
    hipLaunchKernelGGL(xw_gemm, dim3(4096, 16), dim3(256), 0, stream,
                       x, Wx, bx, bh, xw);
    hipLaunchKernelGGL((lstm_scan<true>), dim3(32), dim3(1024), 0, stream,
                       wsu, (const void*)xw, bx, bh, bci, bcf, bco, out);
  } else {
    hipLaunchKernelGGL((lstm_scan<false>), dim3(32), dim3(1024), 0, stream,
                       wsu, (const void*)x, bx, bh, bci, bcf, bco, out);
  }
}

// Round 4
// 13569.754 us; speedup vs baseline: 3.8460x; 3.8460x over previous
//
#include <hip/hip_runtime.h>
#include <cstdint>
#include <cstddef>

// FC_LSTM on MI355X — Round 4: dwordx4 weight loads.
// R3 evidence: scan = 48.65ms, VALUBusy 1.6% (13% on active CUs), HBM ~0,
// ~16 cyc per wave-level vmem instruction (3600 dword loads/step/CU, 57K cyc).
// Theory: per-CU vmem *instruction-rate* bound, not byte bound. Fix: same
// bytes in 4x fewer instructions (global_load_dwordx4, 16B/lane coalesced),
// via chunk-major weight layout: uint4 = 8 f16 of one output row (k-chunk),
// lanes cover consecutive rows. Numerically bit-identical dot ordering.

typedef unsigned short u16;
typedef unsigned int   u32;
typedef float  v4f __attribute__((ext_vector_type(4)));
typedef short  v8s __attribute__((ext_vector_type(8)));
typedef _Float16 h2 __attribute__((ext_vector_type(2)));

#define SEQ 2048
#define NB  32
#define HID 256
#define G4  1024
#define FIN 128
#define COFF (2049*NB*HID)   // element offset of memorys half of d_out

// uint4-unit offsets in ws
#define WH4_OFF  0        // [32][1024] : chunk kc (k=8kc..8kc+7), row n
#define WP4_OFF  32768    // [32][512]  : rows = [Wci n | Wcf n+256]
#define WCO4_OFF 49152    // [32][256]
#define WX4_OFF  57344    // [16][1024] (fallback path)
#define W4_TOTAL 73728    // uint4 count (1.125 MB)

__device__ __forceinline__ u16 f2bf(float f) {
  u32 u = __builtin_bit_cast(u32, f);
  u32 r = (u + 0x7fffu + ((u >> 16) & 1u)) >> 16;
  return (u16)r;
}
__device__ __forceinline__ u16 f2h_bits(float f) {
  _Float16 h = (_Float16)f;
  return __builtin_bit_cast(u16, h);
}
__device__ __forceinline__ u32 pack2f(float a, float b) {
  u32 lo = f2h_bits(a);
  u32 hi = f2h_bits(b);
  return lo | (hi << 16);
}
__device__ __forceinline__ float fd(u32 w, u32 u, float acc) {
  h2 hw = __builtin_bit_cast(h2, w);
  h2 hu = __builtin_bit_cast(h2, u);
  return __builtin_amdgcn_fdot2(hw, hu, acc, false);
}
__device__ __forceinline__ float sigm(float v) { return 1.f / (1.f + __expf(-v)); }
__device__ __forceinline__ float tanh_fast(float x) {
  float xx = fminf(fmaxf(x, -15.f), 15.f);
  float e = __expf(2.f * xx);
  return (e - 1.f) / (e + 1.f);
}

// ---------------- Phase 0: weight repack (f32 -> f16 x8 chunks) -------------
__global__ __launch_bounds__(256) void prep_weights(
    const float* __restrict__ Wh, const float* __restrict__ Wci,
    const float* __restrict__ Wcf, const float* __restrict__ Wco,
    const float* __restrict__ Wx, uint4* __restrict__ ws4)
{
  int i = blockIdx.x * 256 + threadIdx.x;
  if (i >= W4_TOTAL) return;
  const float* src;
  if (i < WP4_OFF) {                       // WhT4
    int kc = i >> 10, n = i & 1023;
    src = Wh + n*256 + kc*8;
  } else if (i < WCO4_OFF) {               // WpT4
    int l = i - WP4_OFF; int kc = l >> 9, n = l & 511;
    src = ((n < 256) ? (Wci + n*256) : (Wcf + (n-256)*256)) + kc*8;
  } else if (i < WX4_OFF) {                // WcoT4
    int l = i - WCO4_OFF; int kc = l >> 8, n = l & 255;
    src = Wco + n*256 + kc*8;
  } else {                                 // WxT4 (fallback)
    int l = i - WX4_OFF; int kc = l >> 10, n = l & 1023;
    src = Wx + n*128 + kc*8;
  }
  uint4 r;
  r.x = pack2f(src[0], src[1]);
  r.y = pack2f(src[2], src[3]);
  r.z = pack2f(src[4], src[5]);
  r.w = pack2f(src[6], src[7]);
  ws4[i] = r;
}

// ---------------- Phase 1: xw GEMM (bf16 MFMA, f32 inputs) ------------------
__global__ __launch_bounds__(256) void xw_gemm(
    const float* __restrict__ x, const float* __restrict__ Wx,
    const float* __restrict__ bx, const float* __restrict__ bh,
    u16* __restrict__ xw)
{
  int wave = threadIdx.x >> 6, lane = threadIdx.x & 63;
  int s = lane & 15, q = lane >> 4;
  int mtile = blockIdx.x;              // 0..4095
  int ntile = blockIdx.y * 4 + wave;   // 0..63
  const float* xa = x  + (size_t)(mtile*16 + s) * 128 + q*8;
  const float* wb = Wx + (size_t)(ntile*16 + s) * 128 + q*8;
  v4f acc = {0.f, 0.f, 0.f, 0.f};
#pragma unroll
  for (int ko = 0; ko < 4; ++ko) {
    float4 a0 = *reinterpret_cast<const float4*>(xa + ko*32);
    float4 a1 = *reinterpret_cast<const float4*>(xa + ko*32 + 4);
    float4 b0 = *reinterpret_cast<const float4*>(wb + ko*32);
    float4 b1 = *reinterpret_cast<const float4*>(wb + ko*32 + 4);
    v8s a, b;
    a[0]=(short)f2bf(a0.x); a[1]=(short)f2bf(a0.y); a[2]=(short)f2bf(a0.z); a[3]=(short)f2bf(a0.w);
    a[4]=(short)f2bf(a1.x); a[5]=(short)f2bf(a1.y); a[6]=(short)f2bf(a1.z); a[7]=(short)f2bf(a1.w);
    b[0]=(short)f2bf(b0.x); b[1]=(short)f2bf(b0.y); b[2]=(short)f2bf(b0.z); b[3]=(short)f2bf(b0.w);
    b[4]=(short)f2bf(b1.x); b[5]=(short)f2bf(b1.y); b[6]=(short)f2bf(b1.z); b[7]=(short)f2bf(b1.w);
    acc = __builtin_amdgcn_mfma_f32_16x16x32_bf16(a, b, acc, 0, 0, 0);
  }
  int n = ntile*16 + s;
  float bias = bx[n] + bh[n];
#pragma unroll
  for (int p = 0; p < 4; ++p) {
    int m = mtile*16 + q*4 + p;
    int bb = m >> 11, t = m & 2047;   // r = b*2048 + t
    xw[(size_t)(t*NB + bb) * G4 + n] = f2h_bits(acc[p] + bias);
  }
}

// ---------------- Phase 2: recurrent scan -----------------------------------
template<bool PRE>
__global__ __launch_bounds__(1024) void lstm_scan(
    const uint4* __restrict__ ws4, const void* __restrict__ xsrc_v,
    const float* __restrict__ bx, const float* __restrict__ bh,
    const float* __restrict__ bci, const float* __restrict__ bcf,
    const float* __restrict__ bco, float* __restrict__ out)
{
  const int b = blockIdx.x, tid = threadIdx.x;
  const uint4* WhT4  = ws4 + WH4_OFF;
  const uint4* WpT4  = ws4 + WP4_OFF;
  const uint4* WcoT4 = ws4 + WCO4_OFF;
  const uint4* WxT4  = ws4 + WX4_OFF;

  __shared__ __align__(16) float s_i[256], s_f[256], s_g[256], s_op[256];
  __shared__ __align__(16) float s_c[256], s_cn[256], s_z[4][256];
  __shared__ __align__(16) u16 s_u[512];    // f16 bits: h [0:256), c [256:512)
  __shared__ __align__(16) u16 s_cnh[256];  // f16 bits of c_new
  __shared__ __align__(16) u16 s_x[128];    // f16 bits of x row (fallback only)
  __shared__ float s_bci[256], s_bcf[256], s_bco[256];
  __shared__ float s_bias[1024];

  if (tid < 256) {
    s_c[tid] = 0.f; s_u[tid] = 0; s_u[256 + tid] = 0;
    s_bci[tid] = bci[tid];
    s_bcf[tid] = bcf[tid];
    s_bco[tid] = bco[tid];
    out[b*HID + tid] = 0.f;          // h0 = 0
    out[COFF + b*HID + tid] = 0.f;   // c0 = 0
  }
  if (!PRE) s_bias[tid] = bx[tid] + bh[tid];
  __syncthreads();

  for (int t = 0; t < SEQ; ++t) {
    u16 xw_raw = 0;
    if (PRE) {
      // prefetch early; consumed after the dot loops (latency hidden)
      const u16* xw = (const u16*)xsrc_v;
      xw_raw = xw[(size_t)(t*NB + b) * G4 + tid];
    } else {
      if (tid < 128) {
        const float* xr = (const float*)xsrc_v + (size_t)(b*SEQ + t) * FIN;
        s_x[tid] = f2h_bits(xr[tid]);
      }
      __syncthreads();
    }

    // y[tid] = h . Wh[tid,:]  (+ c . Wp[tid,:] for i,f cols)
    float acc0 = 0.f, acc1 = 0.f;
#pragma unroll 4
    for (int kc = 0; kc < 32; ++kc) {
      uint4 w  = WhT4[kc*1024 + tid];
      uint4 hh = *reinterpret_cast<const uint4*>(&s_u[8*kc]);
      acc0 = fd(w.x, hh.x, acc0); acc1 = fd(w.y, hh.y, acc1);
      acc0 = fd(w.z, hh.z, acc0); acc1 = fd(w.w, hh.w, acc1);
    }
    if (!PRE) {
#pragma unroll 4
      for (int kc = 0; kc < 16; ++kc) {
        uint4 w  = WxT4[kc*1024 + tid];
        uint4 xx = *reinterpret_cast<const uint4*>(&s_x[8*kc]);
        acc0 = fd(w.x, xx.x, acc0); acc1 = fd(w.y, xx.y, acc1);
        acc0 = fd(w.z, xx.z, acc0); acc1 = fd(w.w, xx.w, acc1);
      }
    }
    if (tid < 512) {  // peephole for i,f over old c (waves 0..7, uniform)
#pragma unroll 4
      for (int kc = 0; kc < 32; ++kc) {
        uint4 w  = WpT4[kc*512 + tid];
        uint4 cc = *reinterpret_cast<const uint4*>(&s_u[256 + 8*kc]);
        acc0 = fd(w.x, cc.x, acc0); acc1 = fd(w.y, cc.y, acc1);
        acc0 = fd(w.z, cc.z, acc0); acc1 = fd(w.w, cc.w, acc1);
      }
    }
    float acc = acc0 + acc1;
    if (PRE) {
      _Float16 hv = __builtin_bit_cast(_Float16, xw_raw);
      acc += (float)hv;
    } else {
      acc += s_bias[tid];
    }

    int gate = tid >> 8, n = tid & 255;
    if (gate == 0)      s_i[n]  = sigm(acc + s_bci[n]);
    else if (gate == 1) s_f[n]  = sigm(acc + s_bcf[n]);
    else if (gate == 2) s_op[n] = acc;                 // bco + peephole later
    else                s_g[n]  = tanh_fast(acc);
    __syncthreads();

    if (tid < 256) {
      float cn = s_f[tid]*s_c[tid] + s_i[tid]*s_g[tid];
      s_cn[tid] = cn; s_c[tid] = cn;
      s_cnh[tid] = f2h_bits(cn);
      out[COFF + (size_t)(t+1)*(NB*HID) + b*HID + tid] = cn;
    }
    __syncthreads();

    {   // o-peephole: z = Wco . c_new, K split 4 ways across the 1024 threads
      int nn = tid & 255, part = tid >> 8;
      float z0 = 0.f, z1 = 0.f;
#pragma unroll
      for (int kc = part*8; kc < part*8 + 8; ++kc) {
        uint4 w  = WcoT4[kc*256 + nn];
        uint4 cc = *reinterpret_cast<const uint4*>(&s_cnh[8*kc]);
        z0 = fd(w.x, cc.x, z0); z1 = fd(w.y, cc.y, z1);
        z0 = fd(w.z, cc.z, z0); z1 = fd(w.w, cc.w, z1);
      }
      s_z[part][nn] = z0 + z1;
    }
    __syncthreads();

    if (tid < 256) {
      float z = s_z[0][tid] + s_z[1][tid] + s_z[2][tid] + s_z[3][tid]
              + s_op[tid] + s_bco[tid];
      float o  = sigm(z);
      float hn = o * tanh_fast(s_cn[tid]);
      out[(size_t)(t+1)*(NB*HID) + b*HID + tid] = hn;
      s_u[tid] = f2h_bits(hn);        // h for next step
      s_u[256 + tid] = s_cnh[tid];    // c for next step
    }
    __syncthreads();
  }
}

// ---------------- launch ----------------------------------------------------
extern "C" void kernel_launch(void* const* d_in, const int* in_sizes, int n_in,
                              void* d_out, int out_size, void* d_ws, size_t ws_size,
                              hipStream_t stream)
{
  const float* x   = (const float*)d_in[0];
  const float* Wx  = (const float*)d_in[1];
  const float* bx  = (const float*)d_in[2];
  const float* Wh  = (const float*)d_in[3];
  const float* bh  = (const float*)d_in[4];
  const float* Wci = (const float*)d_in[5];
  const float* bci = (const float*)d_in[6];
  const float* Wcf = (const float*)d_in[7];
  const float* bcf = (const float*)d_in[8];
  const float* Wco = (const float*)d_in[9];
  const float* bco = (const float*)d_in[10];
  float* out = (float*)d_out;
  uint4* ws4 = (uint4*)d_ws;
  u16* xw  = (u16*)((char*)d_ws + (size_t)W4_TOTAL*16);

  const size_t NEED = (size_t)W4_TOTAL*16 + (size_t)SEQ*NB*G4*2;  // ~129 MB
  const bool pre = (ws_size >= NEED);   // constant across calls -> capture-safe

  hipLaunchKernelGGL(prep_weights, dim3((W4_TOTAL + 255)/256), dim3(256), 0, stream,
                     Wh, Wci, Wcf, Wco, Wx, ws4);
  if (pre) {
    hipLaunchKernelGGL(xw_gemm, dim3(4096, 16), dim3(256), 0, stream,
                       x, Wx, bx, bh, xw);
    hipLaunchKernelGGL((lstm_scan<true>), dim3(32), dim3(1024), 0, stream,
                       ws4, (const void*)xw, bx, bh, bci, bcf, bco, out);
  } else {
    hipLaunchKernelGGL((lstm_scan<false>), dim3(32), dim3(1024), 0, stream,
                       ws4, (const void*)x, bx, bh, bci, bcf, bco, out);
  }
}